// Round 1
// 394.658 us; speedup vs baseline: 1.0358x; 1.0358x over previous
//
#include <hip/hip_runtime.h>

#define H 16
#define S 2048
#define D 64
#define BM 64            // q-rows per block (16 per wave)
#define BN 64            // keys per tile
#define NT (S / BN)      // 32 tiles

typedef __attribute__((ext_vector_type(8))) short bf16x8;
typedef __attribute__((ext_vector_type(4))) short short4v;
typedef __attribute__((ext_vector_type(4))) float fx4;

// fp32 -> bf16 bits, round-to-nearest-even
static __device__ __forceinline__ short f2bf(float x) {
    unsigned u = __float_as_uint(x);
    u += 0x7fffu + ((u >> 16) & 1u);
    return (short)(u >> 16);
}
static __device__ __forceinline__ float bf2f(short s) {
    return __uint_as_float(((unsigned)(unsigned short)s) << 16);
}
// async global->LDS, 16B per lane; dest must be wave-uniform base (+lane*16)
static __device__ __forceinline__ void gl_lds16(const void* g, void* l) {
    __builtin_amdgcn_global_load_lds(
        (const __attribute__((address_space(1))) unsigned int*)g,
        (__attribute__((address_space(3))) unsigned int*)l, 16, 0, 0);
}

// ---------------- pass 1: K -> (khi,klo) bf16 [H][S][D]; V -> vt bf16 [H][D][S] ----------------
__global__ __launch_bounds__(256)
void ParallelRetention_prep_kernel(
    const float* __restrict__ k, const float* __restrict__ v,
    short* __restrict__ khi, short* __restrict__ klo, short* __restrict__ vt)
{
    __shared__ short lv[64 * 72];     // V^T staging tile, padded pitch
    const int tid = threadIdx.x;
    const int h  = blockIdx.x & 15;
    const int sb = blockIdx.x >> 4;
    const int s0 = sb * 64;
    const int t_base = (tid >> 4) << 2;   // 0..60
    const int d4     = (tid & 15) << 2;   // 0..60
    const size_t hoff = (size_t)h * S * D;

    // K: hi/lo split, layout preserved
    {
        const float* kb = k + hoff + (size_t)(s0 + t_base) * D + d4;
#pragma unroll
        for (int r = 0; r < 4; ++r) {
            fx4 kr = *(const fx4*)(kb + (size_t)r * D);
            short4v h4, l4;
#pragma unroll
            for (int j = 0; j < 4; ++j) {
                short hi = f2bf(kr[j]);
                h4[j] = hi;
                l4[j] = f2bf(kr[j] - bf2f(hi));
            }
            *(short4v*)(&khi[hoff + (size_t)(s0 + t_base + r) * D + d4]) = h4;
            *(short4v*)(&klo[hoff + (size_t)(s0 + t_base + r) * D + d4]) = l4;
        }
    }
    // V: bf16 + transpose via LDS
    {
        const float* vb = v + hoff + (size_t)(s0 + t_base) * D + d4;
        fx4 vr[4];
#pragma unroll
        for (int r = 0; r < 4; ++r) vr[r] = *(const fx4*)(vb + (size_t)r * D);
#pragma unroll
        for (int j = 0; j < 4; ++j) {
            short4v p;
#pragma unroll
            for (int r = 0; r < 4; ++r) p[r] = f2bf(vr[r][j]);
            *(short4v*)(&lv[(d4 + j) * 72 + t_base]) = p;
        }
    }
    __syncthreads();
    {
        const int d = tid >> 2;
        const int c = tid & 3;
        bf16x8 a = *(const bf16x8*)(&lv[d * 72 + c * 16]);
        bf16x8 b = *(const bf16x8*)(&lv[d * 72 + c * 16 + 8]);
        short* o = vt + (size_t)h * D * S + (size_t)d * S + s0 + c * 16;
        *(bf16x8*)(o)     = a;
        *(bf16x8*)(o + 8) = b;
    }
}

// ---------------- pass 2: main retention kernel ----------------
// LDS tiles are LINEAR 64x64 bf16 (128B rows) for global_load_lds; the bank
// swizzle elem ^= ((row&7)<<3) is applied on the GLOBAL source address at
// staging time and on every ds_read/ds_write address (both-sides rule).
__global__ __launch_bounds__(256, 2)
void ParallelRetention_origin_25374666785438_kernel(
    const float* __restrict__ q, const float* __restrict__ om,
    const short* __restrict__ khi, const short* __restrict__ klo,
    const short* __restrict__ vt, float* __restrict__ out)
{
    __shared__ short ldsKh[2][64 * 64];
    __shared__ short ldsKl[2][64 * 64];
    __shared__ short ldsVT[2][64 * 64];
    __shared__ short ldsP[64 * 64];       // wave-private 16-row stripes; total LDS 56 KB

    const int tid  = threadIdx.x;
    const int wave = tid >> 6;
    const int lane = tid & 63;
    const int col  = lane & 15;
    const int quad = lane >> 4;

    const int h  = blockIdx.x & 15;      // same-head blocks land on one XCD (stride 16 % 8 == 0)
    const int qb = blockIdx.x >> 4;
    const int row0 = qb * BM;

    const size_t headQK = (size_t)h * S * D;
    const size_t headM  = (size_t)h * S * S;

    // ---- Q fragments (A/B layouts symmetric: same regs serve as B-operand) ----
    bf16x8 qh[2], qlo[2];
    {
        const int s_row = row0 + wave * 16 + col;
        const float* qp = q + headQK + (size_t)s_row * D + quad * 8;
#pragma unroll
        for (int c = 0; c < 2; ++c) {
            fx4 a = *(const fx4*)(qp + c * 32);
            fx4 b = *(const fx4*)(qp + c * 32 + 4);
            float f[8] = {a[0],a[1],a[2],a[3],b[0],b[1],b[2],b[3]};
#pragma unroll
            for (int j = 0; j < 8; ++j) {
                short hi = f2bf(f[j]);
                qh[c][j]  = hi;
                qlo[c][j] = f2bf(f[j] - bf2f(hi));
            }
        }
    }

    fx4 U[4];
#pragma unroll
    for (int nt = 0; nt < 4; ++nt) { U[nt][0]=0.f; U[nt][1]=0.f; U[nt][2]=0.f; U[nt][3]=0.f; }
    float rs_acc = 0.f, T_acc = 0.f;      // per-lane: q-row = col (swapped layout)

    // swizzled LDS element offsets (row pitch 64 elems)
    const int xq   = quad ^ (col & 3);
    const int cx   = (col >> 2) & 1;
    const int rdC0 = col * 64 + xq * 8 + cx * 32;        // K/VT read, k-chunk 0
    const int rdC1 = col * 64 + xq * 8 + (cx ^ 1) * 32;  // k-chunk 1
    const int prow   = wave * 16 + col;
    const int pwBase = prow * 64 + (quad & 1) * 4 + (((quad >> 1) ^ (col & 1))) * 8;
    const int pxor   = (col >> 1) & 3;
    const int prC0   = prow * 64 + xq * 8 + cx * 32;
    const int prC1   = prow * 64 + xq * 8 + (cx ^ 1) * 32;
    // staging per-lane source offsets (inverse swizzle on global address)
    const int rowl = lane >> 3;                    // 0..7 within 8-row chunk
    const int swz8 = ((lane & 7) ^ rowl) * 8;
    const int kSrcOff = rowl * 64 + swz8;          // khi/klo rows are 64 elems
    const int vSrcOff = rowl * 2048 + swz8;        // vt rows are S elems

    const short* khiH = khi + headQK;
    const short* kloH = klo + headQK;
    const short* vtH  = vt + (size_t)h * D * S;
    const float* omp0 = om + headM + (size_t)(row0 + wave * 16 + col) * S + quad * 4;

    auto stage = [&](int t0, short* dKh, short* dKl, short* dVT) {
        const short* ks = khiH + (size_t)t0 * 64 + kSrcOff;
        const short* ls = kloH + (size_t)t0 * 64 + kSrcOff;
        const short* vs = vtH + t0 + vSrcOff;
#pragma unroll
        for (int c = 0; c < 6; ++c) {       // 24 1KB chunks split over 4 waves
            int id = wave * 6 + c;
            int j  = id & 7;
            int tile = id >> 3;
            if (tile == 0)      gl_lds16(ks + j * 512, dKh + j * 512);
            else if (tile == 1) gl_lds16(ls + j * 512, dKl + j * 512);
            else                gl_lds16(vs + (size_t)j * 8 * 2048, dVT + j * 512);
        }
    };
    auto load_om = [&](int t0, fx4 (&o)[4]) {
#pragma unroll
        for (int tn = 0; tn < 4; ++tn)
            o[tn] = *(const fx4*)(omp0 + t0 + tn * 16);   // 4 consecutive t per lane
    };
    auto compute = [&](const short* Kh, const short* Kl, const short* VT,
                       const fx4 (&omc)[4]) {
#pragma unroll
        for (int tn = 0; tn < 4; ++tn) {
            bf16x8 kh0 = *(const bf16x8*)(&Kh[tn * 1024 + rdC0]);
            bf16x8 kh1 = *(const bf16x8*)(&Kh[tn * 1024 + rdC1]);
            bf16x8 kl0 = *(const bf16x8*)(&Kl[tn * 1024 + rdC0]);
            bf16x8 kl1 = *(const bf16x8*)(&Kl[tn * 1024 + rdC1]);
            fx4 z; z[0]=0.f; z[1]=0.f; z[2]=0.f; z[3]=0.f;
            // swapped operands: D[row = t (quad*4+r)][col = q]
            z = __builtin_amdgcn_mfma_f32_16x16x32_bf16(kh0, qh[0],  z, 0, 0, 0);
            z = __builtin_amdgcn_mfma_f32_16x16x32_bf16(kh1, qh[1],  z, 0, 0, 0);
            z = __builtin_amdgcn_mfma_f32_16x16x32_bf16(kl0, qh[0],  z, 0, 0, 0);
            z = __builtin_amdgcn_mfma_f32_16x16x32_bf16(kl1, qh[1],  z, 0, 0, 0);
            z = __builtin_amdgcn_mfma_f32_16x16x32_bf16(kh0, qlo[0], z, 0, 0, 0);
            z = __builtin_amdgcn_mfma_f32_16x16x32_bf16(kh1, qlo[1], z, 0, 0, 0);
            short4v p4;
#pragma unroll
            for (int r = 0; r < 4; ++r) {
                float m = omc[tn][r];
                float p = z[r] * m;
                rs_acc += m;
                T_acc  += p;
                p4[r] = f2bf(p);
            }
            *(short4v*)(&ldsP[pwBase + ((tn ^ pxor) << 4)]) = p4;  // 4 consecutive t, b64
        }
        bf16x8 pa0 = *(const bf16x8*)(&ldsP[prC0]);
        bf16x8 pa1 = *(const bf16x8*)(&ldsP[prC1]);
#pragma unroll
        for (int nt = 0; nt < 4; ++nt) {
            bf16x8 vb0 = *(const bf16x8*)(&VT[nt * 1024 + rdC0]);
            bf16x8 vb1 = *(const bf16x8*)(&VT[nt * 1024 + rdC1]);
            U[nt] = __builtin_amdgcn_mfma_f32_16x16x32_bf16(pa0, vb0, U[nt], 0, 0, 0);
            U[nt] = __builtin_amdgcn_mfma_f32_16x16x32_bf16(pa1, vb1, U[nt], 0, 0, 0);
        }
    };

    // ---- prologue ----
    fx4 omA[4], omB[4];
    stage(0, &ldsKh[0][0], &ldsKl[0][0], &ldsVT[0][0]);
    load_om(0, omA);

    // ---- pipelined main loop (2-step unroll keeps om regs statically indexed) ----
    for (int t = 0; t < NT; t += 2) {
        __syncthreads();                       // drains vmcnt: buf0 staged
        if (t + 1 < NT) {
            stage((t + 1) * BN, &ldsKh[1][0], &ldsKl[1][0], &ldsVT[1][0]);
            load_om((t + 1) * BN, omB);
        }
        compute(&ldsKh[0][0], &ldsKl[0][0], &ldsVT[0][0], omA);
        __syncthreads();                       // buf1 staged
        if (t + 2 < NT) {
            stage((t + 2) * BN, &ldsKh[0][0], &ldsKl[0][0], &ldsVT[0][0]);
            load_om((t + 2) * BN, omA);
        }
        compute(&ldsKh[1][0], &ldsKl[1][0], &ldsVT[1][0], omB);
    }

    // ---- epilogue: totals for q=col live across the 4 quads -> 2 shuffles ----
    rs_acc += __shfl_xor(rs_acc, 16, 64);
    rs_acc += __shfl_xor(rs_acc, 32, 64);
    T_acc  += __shfl_xor(T_acc, 16, 64);
    T_acc  += __shfl_xor(T_acc, 32, 64);
    float inv = rs_acc > 0.f ? rsqrtf(rs_acc) : 0.f;
    float rowsum = T_acc * inv;
    float sc = fabsf(rowsum);
    sc = sc < 1.f ? 1.f : sc;
    float fac = inv / sc;
    // U row index is q = quad*4+r; fetch that q's factor from lane (quad*4+r)
    float f[4];
#pragma unroll
    for (int r = 0; r < 4; ++r) f[r] = __shfl(fac, quad * 4 + r, 64);
    float* op = out + headQK + (size_t)(row0 + wave * 16) * D;
#pragma unroll
    for (int r = 0; r < 4; ++r)
#pragma unroll
        for (int nt = 0; nt < 4; ++nt)
            op[(size_t)(quad * 4 + r) * D + nt * 16 + col] = U[nt][r] * f[r];
}

extern "C" void kernel_launch(void* const* d_in, const int* in_sizes, int n_in,
                              void* d_out, int out_size, void* d_ws, size_t ws_size,
                              hipStream_t stream) {
    const float* q  = (const float*)d_in[0];
    const float* k  = (const float*)d_in[1];
    const float* v  = (const float*)d_in[2];
    const float* om = (const float*)d_in[3];
    float* out = (float*)d_out;
    (void)in_sizes; (void)n_in; (void)out_size; (void)ws_size;

    // workspace: khi | klo | vt  (3 x 4 MB bf16)
    short* khi = (short*)d_ws;
    short* klo = khi + (size_t)H * S * D;
    short* vt  = klo + (size_t)H * S * D;

    hipLaunchKernelGGL(ParallelRetention_prep_kernel,
                       dim3(H * (S / 64)), dim3(256), 0, stream, k, v, khi, klo, vt);
    hipLaunchKernelGGL(ParallelRetention_origin_25374666785438_kernel,
                       dim3(H * (S / BM)), dim3(256), 0, stream, q, om, khi, klo, vt, out);
}